// Round 20
// baseline (311.280 us; speedup 1.0000x reference)
//
#include <hip/hip_runtime.h>
#include <hip/hip_bf16.h>
#include <hip/hip_fp16.h>

#define N_NODES 50000
#define IN_DIM 768
#define HID 128
#define NCLS 32
#define CHUNK 8192                        // edges per chunk-block
#define NBUCK ((N_NODES + 255) >> 8)      // 196 coarse buckets (256 nodes each)

typedef __attribute__((ext_vector_type(8))) short bf16x8;
typedef __attribute__((ext_vector_type(4))) float f32x4;
typedef __attribute__((ext_vector_type(4))) unsigned short u16x4;

__device__ inline void split_bf16(float x, unsigned short& hi, unsigned short& lo) {
    unsigned int u = __float_as_uint(x);
    hi = (unsigned short)(u >> 16);
    float r = x - __uint_as_float(u & 0xFFFF0000u);
    lo = (unsigned short)(__float_as_uint(r) >> 16);
}

__device__ inline void split4(const float4& v, u16x4& h, u16x4& lo) {
    split_bf16(v.x, ((unsigned short*)&h)[0], ((unsigned short*)&lo)[0]);
    split_bf16(v.y, ((unsigned short*)&h)[1], ((unsigned short*)&lo)[1]);
    split_bf16(v.z, ((unsigned short*)&h)[2], ((unsigned short*)&lo)[2]);
    split_bf16(v.w, ((unsigned short*)&h)[3], ((unsigned short*)&lo)[3]);
}

// ---------------- pass 1: coarse bucket histogram (LDS only) -----------------
__global__ __launch_bounds__(256) void count_bucket(const int* __restrict__ raw, int E,
                                                    int* __restrict__ hist) {
    __shared__ int cnt[NBUCK];
    bool is64 = (raw[1] == 0 && raw[3] == 0 && raw[5] == 0 && raw[7] == 0);
    int t = threadIdx.x, b = blockIdx.x;
    if (t < NBUCK) cnt[t] = 0;
    __syncthreads();
    int base = b * CHUNK;
#pragma unroll
    for (int j = 0; j < CHUNK / 256; ++j) {
        int e = base + j * 256 + t;
        if (e < E) {
            int d = is64 ? raw[2 * (E + e)] : raw[E + e];
            atomicAdd(&cnt[d >> 8], 1);
        }
    }
    __syncthreads();
    if (t < NBUCK) hist[b * NBUCK + t] = cnt[t];
}

// ---------------- pass 2: bucket starts + per-(block,bucket) offsets ---------
__global__ __launch_bounds__(256) void scan_off2(const int* __restrict__ hist, int nblk,
                                                 int E, int* __restrict__ bstart,
                                                 int* __restrict__ off) {
    __shared__ int tot[256];
    int t = threadIdx.x;
    int sum = 0;
    if (t < NBUCK)
        for (int b = 0; b < nblk; ++b) sum += hist[b * NBUCK + t];
    tot[t] = (t < NBUCK) ? sum : 0;
    __syncthreads();
    for (int o = 1; o < 256; o <<= 1) {
        int v = (t >= o) ? tot[t - o] : 0;
        __syncthreads();
        tot[t] += v;
        __syncthreads();
    }
    int excl = (t == 0) ? 0 : tot[t - 1];
    if (t < NBUCK) {
        bstart[t] = excl;
        int run = excl;
        for (int b = 0; b < nblk; ++b) {
            off[b * NBUCK + t] = run;
            run += hist[b * NBUCK + t];
        }
    }
    if (t == 0) bstart[NBUCK] = E;
}

// ---------------- pass 3: chunk scatter into bucket-sorted packed ebuf -------
// ebuf entry u32 = (dst_local:8 << 16) | src:16   (N_NODES < 65536)
__global__ __launch_bounds__(256) void chunk_scatter(const int* __restrict__ raw, int E,
                                                     const int* __restrict__ off,
                                                     unsigned int* __restrict__ ebuf) {
    __shared__ int offl[NBUCK];
    __shared__ int cnt[NBUCK];
    bool is64 = (raw[1] == 0 && raw[3] == 0 && raw[5] == 0 && raw[7] == 0);
    int t = threadIdx.x, b = blockIdx.x;
    if (t < NBUCK) { offl[t] = off[b * NBUCK + t]; cnt[t] = 0; }
    __syncthreads();
    int base = b * CHUNK;
#pragma unroll
    for (int j = 0; j < CHUNK / 256; ++j) {
        int e = base + j * 256 + t;
        if (e < E) {
            int s, d;
            if (is64) { s = raw[2 * e]; d = raw[2 * (E + e)]; }
            else      { s = raw[e];     d = raw[E + e]; }
            int k = d >> 8;
            int r = atomicAdd(&cnt[k], 1);
            ebuf[offl[k] + r] = ((unsigned int)(d & 255) << 16) | (unsigned int)s;
        }
    }
}

// ---------------- pass 4: per-bucket deg/rowp/dinv + fine scatter (u16 csr) --
__global__ __launch_bounds__(256) void bucket_fine2(const unsigned int* __restrict__ ebuf,
                                                    const int* __restrict__ bstart,
                                                    int* __restrict__ rowp,
                                                    float* __restrict__ dinv,
                                                    unsigned short* __restrict__ csr,
                                                    int n, int E) {
    __shared__ int cnt[256];
    __shared__ int pre[256];
    __shared__ int fil[256];
    int k = blockIdx.x, t = threadIdx.x;
    int base = k << 8;
    int nn = min(256, n - base);
    int es = bstart[k], ee = bstart[k + 1];
    cnt[t] = 0;
    __syncthreads();
    for (int p = es + t; p < ee; p += 256) atomicAdd(&cnt[ebuf[p] >> 16], 1);
    __syncthreads();
    pre[t] = cnt[t];
    __syncthreads();
    for (int o = 1; o < 256; o <<= 1) {
        int v = (t >= o) ? pre[t - o] : 0;
        __syncthreads();
        pre[t] += v;
        __syncthreads();
    }
    int excl = (t == 0) ? 0 : pre[t - 1];
    if (t < nn) {
        rowp[base + t] = es + excl;
        dinv[base + t] = rsqrtf((float)(cnt[t] + 1));  // +1 = self-loop
    }
    if (k == gridDim.x - 1 && t == 0) rowp[n] = E;
    fil[t] = es + excl;
    __syncthreads();
    for (int p = es + t; p < ee; p += 256) {
        unsigned int u = ebuf[p];
        int q = atomicAdd(&fil[u >> 16], 1);
        csr[q] = (unsigned short)(u & 0xFFFFu);
    }
}

// ---------------- weight pack: W[K][128] f32 -> fragment-order split bf16 -----
__global__ void pack_w(const float* __restrict__ W, int K,
                       unsigned short* __restrict__ ph, unsigned short* __restrict__ pl) {
    int gid = blockIdx.x * 256 + threadIdx.x;
    int total = (K / 32) * 8 * 64;
    if (gid >= total) return;
    int l = gid & 63;
    int c0 = (gid >> 6) & 7;
    int t = gid >> 9;
    int col = c0 * 16 + (l & 15);
    int k0 = t * 32 + ((l >> 4) << 3);
    size_t base = (size_t)gid * 8;
#pragma unroll
    for (int j = 0; j < 8; ++j) {
        unsigned short h, lo;
        split_bf16(W[(size_t)(k0 + j) * 128 + col], h, lo);
        ph[base + j] = h;
        pl[base + j] = lo;
    }
}

template <bool AHALF>
__device__ inline float4 loadA4(const void* A, size_t idx) {
    if constexpr (AHALF) {
        uint2 u = *(const uint2*)((const __half*)A + idx);
        float2 f0 = __half22float2(*(__half2*)&u.x);
        float2 f1 = __half22float2(*(__half2*)&u.y);
        return make_float4(f0.x, f0.y, f1.x, f1.y);
    } else {
        return *(const float4*)((const float*)A + idx);
    }
}

// -- split-bf16 MFMA GEMM (BKT=32 = proven best): ht = dinv ⊙ (A@B), fp16 -----
template <int K, int BKT, bool AHALF>
__global__ __launch_bounds__(256) void gemm_mfma8(const void* __restrict__ A,
                                                  const unsigned short* __restrict__ Bph,
                                                  const unsigned short* __restrict__ Bpl,
                                                  const float* __restrict__ dinv,
                                                  __half* __restrict__ Chalf, int M) {
    constexpr int QPR = BKT / 4;             // float4 quads per row
    constexpr int NQ = 64 * QPR / 256;       // quads per thread
    constexpr int NSUB = BKT / 32;           // 32-wide sub-tiles per step
    __shared__ unsigned short Ah[64][BKT + 8];
    __shared__ unsigned short Al[64][BKT + 8];
    int tid = threadIdx.x;
    int wid = tid >> 6, lane = tid & 63;
    int wr = wid >> 1, wc = wid & 1;         // wave grid 2x2
    int row0 = blockIdx.x * 64;
    int lrow = lane & 15;
    const int T = K / BKT;

    int sr[NQ], sc[NQ];
    bool vv[NQ];
    size_t ai[NQ];
#pragma unroll
    for (int q = 0; q < NQ; ++q) {
        int idx = q * 256 + tid;
        sr[q] = idx / QPR;
        sc[q] = (idx % QPR) * 4;
        vv[q] = (row0 + sr[q]) < M;
        ai[q] = (size_t)(row0 + sr[q]) * K + sc[q];
    }

    float4 z = make_float4(0.f, 0.f, 0.f, 0.f);
    float4 pre[NQ];
#pragma unroll
    for (int q = 0; q < NQ; ++q) pre[q] = vv[q] ? loadA4<AHALF>(A, ai[q]) : z;

    f32x4 acc[2][4] = {};
    for (int t = 0; t < T; ++t) {
        // split staged regs -> LDS
#pragma unroll
        for (int q = 0; q < NQ; ++q) {
            u16x4 h, lo;
            split4(pre[q], h, lo);
            *(u16x4*)&Ah[sr[q]][sc[q]] = h;
            *(u16x4*)&Al[sr[q]][sc[q]] = lo;
        }
        __syncthreads();
#pragma unroll
        for (int ks = 0; ks < NSUB; ++ks) {
            int lk2 = ks * 32 + (lane >> 4) * 8;
            bf16x8 bh[4], bl[4];
#pragma unroll
            for (int n = 0; n < 4; ++n) {
                size_t boff = ((size_t)((t * NSUB + ks) * 8 + wc * 4 + n) * 64 + lane) * 8;
                bh[n] = *(const bf16x8*)&Bph[boff];
                bl[n] = *(const bf16x8*)&Bpl[boff];
            }
            if (ks == 0 && t + 1 < T) {
#pragma unroll
                for (int q = 0; q < NQ; ++q)
                    pre[q] = vv[q] ? loadA4<AHALF>(A, ai[q] + (size_t)(t + 1) * BKT) : z;
            }
            bf16x8 ah[2], al[2];
#pragma unroll
            for (int m = 0; m < 2; ++m) {
                int r = wr * 32 + m * 16 + lrow;
                ah[m] = *(const bf16x8*)&Ah[r][lk2];
                al[m] = *(const bf16x8*)&Al[r][lk2];
            }
#pragma unroll
            for (int m = 0; m < 2; ++m)
#pragma unroll
                for (int n = 0; n < 4; ++n) {
                    acc[m][n] = __builtin_amdgcn_mfma_f32_16x16x32_bf16(ah[m], bh[n], acc[m][n], 0, 0, 0);
                    acc[m][n] = __builtin_amdgcn_mfma_f32_16x16x32_bf16(al[m], bh[n], acc[m][n], 0, 0, 0);
                    acc[m][n] = __builtin_amdgcn_mfma_f32_16x16x32_bf16(ah[m], bl[n], acc[m][n], 0, 0, 0);
                }
        }
        __syncthreads();
    }
    // epilogue: ht = dinv[r] * acc, fp16. C/D layout: col=lane&15, row=(lane>>4)*4+j
#pragma unroll
    for (int m = 0; m < 2; ++m) {
        int rbase = row0 + wr * 32 + m * 16 + (lane >> 4) * 4;
#pragma unroll
        for (int n = 0; n < 4; ++n) {
            int col = wc * 64 + n * 16 + lrow;
#pragma unroll
            for (int j = 0; j < 4; ++j) {
                int r = rbase + j;
                if (r < M) Chalf[(size_t)r * 128 + col] = __float2half(dinv[r] * acc[m][n][j]);
            }
        }
    }
}

// ------- aggregation: wave-per-node, pre-scaled fp16 table, unroll-32 --------
// out[i] = relu(di * (ht[i] + sum_s ht[s]) + b), written fp16
__global__ __launch_bounds__(256) void aggregate6(const __half* __restrict__ ht,
                                                  const int* __restrict__ rowp,
                                                  const unsigned short* __restrict__ csr,
                                                  const float* __restrict__ dinv,
                                                  const float* __restrict__ bias,
                                                  __half* __restrict__ outh, int n) {
    int wid = threadIdx.x >> 6, lane = threadIdx.x & 63;
    int i = blockIdx.x * 4 + wid;
    if (i >= n) return;
    const __half2* h2 = (const __half2*)ht;  // [n][64] half2
    float di = dinv[i];
    float2 acc = __half22float2(h2[(size_t)i * 64 + lane]);  // self (pre-scaled)
    int b = rowp[i], e = rowp[i + 1];
    int p = b;
    for (; p + 32 <= e; p += 32) {
        int s[32]; float2 v[32];
#pragma unroll
        for (int q = 0; q < 32; ++q) s[q] = csr[p + q];
#pragma unroll
        for (int q = 0; q < 32; ++q) v[q] = __half22float2(h2[(size_t)s[q] * 64 + lane]);
#pragma unroll
        for (int q = 0; q < 32; ++q) { acc.x += v[q].x; acc.y += v[q].y; }
    }
    for (; p + 8 <= e; p += 8) {
        int s[8]; float2 v[8];
#pragma unroll
        for (int q = 0; q < 8; ++q) s[q] = csr[p + q];
#pragma unroll
        for (int q = 0; q < 8; ++q) v[q] = __half22float2(h2[(size_t)s[q] * 64 + lane]);
#pragma unroll
        for (int q = 0; q < 8; ++q) { acc.x += v[q].x; acc.y += v[q].y; }
    }
    for (; p < e; ++p) {
        float2 v = __half22float2(h2[(size_t)csr[p] * 64 + lane]);
        acc.x += v.x;
        acc.y += v.y;
    }
    float2 bb = ((const float2*)bias)[lane];
    __half2 o = __floats2half2_rn(fmaxf(di * acc.x + bb.x, 0.f),
                                  fmaxf(di * acc.y + bb.y, 0.f));
    ((__half2*)outh)[(size_t)i * 64 + lane] = o;
}

// ---------------- final FC: out[N,32] = h(fp16)[N,128] @ Wfc[128,32] + bfc ---
__global__ __launch_bounds__(256) void fc_out(const __half* __restrict__ h,
                                              const float* __restrict__ W,
                                              const float* __restrict__ b,
                                              float* __restrict__ out, int n) {
    __shared__ float Ws[HID * NCLS];
    __shared__ float Hs[8][HID];
    int tid = threadIdx.x;
#pragma unroll
    for (int l = 0; l < 16; ++l) Ws[l * 256 + tid] = W[l * 256 + tid];
    int row0 = blockIdx.x * 8;
#pragma unroll
    for (int l = 0; l < 4; ++l) {
        int idx = l * 256 + tid;
        int r = idx >> 7, c = idx & 127;
        int gr = row0 + r;
        Hs[r][c] = (gr < n) ? __half2float(h[(size_t)gr * HID + c]) : 0.f;
    }
    __syncthreads();
    int r = tid >> 5, c = tid & 31;
    float acc = b[c];
#pragma unroll
    for (int k = 0; k < HID; ++k) acc += Hs[r][k] * Ws[k * NCLS + c];
    int gr = row0 + r;
    if (gr < n) out[(size_t)gr * NCLS + c] = acc;
}

extern "C" void kernel_launch(void* const* d_in, const int* in_sizes, int n_in,
                              void* d_out, int out_size, void* d_ws, size_t ws_size,
                              hipStream_t stream) {
    const float* x   = (const float*)d_in[0];
    const int*   eid = (const int*)d_in[1];
    const float* W1  = (const float*)d_in[2];
    const float* b1  = (const float*)d_in[3];
    const float* W2  = (const float*)d_in[4];
    const float* b2  = (const float*)d_in[5];
    const float* Wfc = (const float*)d_in[6];
    const float* bfc = (const float*)d_in[7];
    float* out = (float*)d_out;

    const int N = N_NODES;
    const int E = in_sizes[1] / 2;
    const int NBLK = (E + CHUNK - 1) / CHUNK;

    auto align = [](size_t v) { return (v + 255) & ~(size_t)255; };
    char* w = (char*)d_ws;
    size_t off = 0;
    int* rowp = (int*)(w + off);           off = align(off + (size_t)(N + 1) * 4);
    float* dinv = (float*)(w + off);       off = align(off + (size_t)N * 4);
    unsigned short* csr = (unsigned short*)(w + off); off = align(off + (size_t)E * 2);
    unsigned int* ebuf = (unsigned int*)(w + off);    off = align(off + (size_t)E * 4);
    int* bstart = (int*)(w + off);         off = align(off + (size_t)(NBUCK + 1) * 4);
    int* hist = (int*)(w + off);           off = align(off + (size_t)NBLK * NBUCK * 4);
    int* offs = (int*)(w + off);           off = align(off + (size_t)NBLK * NBUCK * 4);
    unsigned short* W1ph = (unsigned short*)(w + off); off = align(off + (size_t)128 * IN_DIM * 2);
    unsigned short* W1pl = (unsigned short*)(w + off); off = align(off + (size_t)128 * IN_DIM * 2);
    unsigned short* W2ph = (unsigned short*)(w + off); off = align(off + (size_t)128 * HID * 2);
    unsigned short* W2pl = (unsigned short*)(w + off); off = align(off + (size_t)128 * HID * 2);
    __half* ht1 = (__half*)(w + off);      off = align(off + (size_t)N * HID * 2);
    __half* ht2 = (__half*)(w + off);      off = align(off + (size_t)N * HID * 2);
    __half* h1r = (__half*)(w + off);      off = align(off + (size_t)N * HID * 2);
    __half* h2r = (__half*)(w + off);      off = align(off + (size_t)N * HID * 2);

    count_bucket<<<NBLK, 256, 0, stream>>>(eid, E, hist);
    scan_off2<<<1, 256, 0, stream>>>(hist, NBLK, E, bstart, offs);
    chunk_scatter<<<NBLK, 256, 0, stream>>>(eid, E, offs, ebuf);
    bucket_fine2<<<NBUCK, 256, 0, stream>>>(ebuf, bstart, rowp, dinv, csr, N, E);

    pack_w<<<((IN_DIM / 32) * 8 * 64 + 255) / 256, 256, 0, stream>>>(W1, IN_DIM, W1ph, W1pl);
    pack_w<<<((HID / 32) * 8 * 64 + 255) / 256, 256, 0, stream>>>(W2, HID, W2ph, W2pl);

    int gb = (N + 63) / 64;
    int ab = (N + 3) / 4;
    gemm_mfma8<IN_DIM, 32, false><<<gb, 256, 0, stream>>>(x, W1ph, W1pl, dinv, ht1, N);
    aggregate6<<<ab, 256, 0, stream>>>(ht1, rowp, csr, dinv, b1, h1r, N);
    gemm_mfma8<HID, 32, true><<<gb, 256, 0, stream>>>(h1r, W2ph, W2pl, dinv, ht2, N);
    aggregate6<<<ab, 256, 0, stream>>>(ht2, rowp, csr, dinv, b2, h2r, N);
    fc_out<<<(N + 7) / 8, 256, 0, stream>>>(h2r, Wfc, bfc, out, N);
}

// Round 21
// 280.347 us; speedup vs baseline: 1.1103x; 1.1103x over previous
//
#include <hip/hip_runtime.h>
#include <hip/hip_bf16.h>
#include <hip/hip_fp16.h>

#define N_NODES 50000
#define IN_DIM 768
#define HID 128
#define NCLS 32
#define CHUNK 8192                        // edges per chunk-block
#define NBUCK ((N_NODES + 255) >> 8)      // 196 coarse buckets (256 nodes each)

typedef __attribute__((ext_vector_type(8))) short bf16x8;
typedef __attribute__((ext_vector_type(4))) float f32x4;
typedef __attribute__((ext_vector_type(4))) unsigned short u16x4;

__device__ inline void split_bf16(float x, unsigned short& hi, unsigned short& lo) {
    unsigned int u = __float_as_uint(x);
    hi = (unsigned short)(u >> 16);
    float r = x - __uint_as_float(u & 0xFFFF0000u);
    lo = (unsigned short)(__float_as_uint(r) >> 16);
}

// ---------------- pass 1: coarse bucket histogram (LDS only) -----------------
__global__ __launch_bounds__(256) void count_bucket(const int* __restrict__ raw, int E,
                                                    int* __restrict__ hist) {
    __shared__ int cnt[NBUCK];
    bool is64 = (raw[1] == 0 && raw[3] == 0 && raw[5] == 0 && raw[7] == 0);
    int t = threadIdx.x, b = blockIdx.x;
    if (t < NBUCK) cnt[t] = 0;
    __syncthreads();
    int base = b * CHUNK;
#pragma unroll
    for (int j = 0; j < CHUNK / 256; ++j) {
        int e = base + j * 256 + t;
        if (e < E) {
            int d = is64 ? raw[2 * (E + e)] : raw[E + e];
            atomicAdd(&cnt[d >> 8], 1);
        }
    }
    __syncthreads();
    if (t < NBUCK) hist[b * NBUCK + t] = cnt[t];
}

// ---------------- pass 2: bucket starts + per-(block,bucket) offsets ---------
__global__ __launch_bounds__(256) void scan_off2(const int* __restrict__ hist, int nblk,
                                                 int E, int* __restrict__ bstart,
                                                 int* __restrict__ off) {
    __shared__ int tot[256];
    int t = threadIdx.x;
    int sum = 0;
    if (t < NBUCK)
        for (int b = 0; b < nblk; ++b) sum += hist[b * NBUCK + t];
    tot[t] = (t < NBUCK) ? sum : 0;
    __syncthreads();
    for (int o = 1; o < 256; o <<= 1) {
        int v = (t >= o) ? tot[t - o] : 0;
        __syncthreads();
        tot[t] += v;
        __syncthreads();
    }
    int excl = (t == 0) ? 0 : tot[t - 1];
    if (t < NBUCK) {
        bstart[t] = excl;
        int run = excl;
        for (int b = 0; b < nblk; ++b) {
            off[b * NBUCK + t] = run;
            run += hist[b * NBUCK + t];
        }
    }
    if (t == 0) bstart[NBUCK] = E;
}

// ---------------- pass 3: chunk scatter into bucket-sorted packed ebuf -------
// ebuf entry u32 = (dst_local:8 << 16) | src:16   (N_NODES < 65536)
__global__ __launch_bounds__(256) void chunk_scatter(const int* __restrict__ raw, int E,
                                                     const int* __restrict__ off,
                                                     unsigned int* __restrict__ ebuf) {
    __shared__ int offl[NBUCK];
    __shared__ int cnt[NBUCK];
    bool is64 = (raw[1] == 0 && raw[3] == 0 && raw[5] == 0 && raw[7] == 0);
    int t = threadIdx.x, b = blockIdx.x;
    if (t < NBUCK) { offl[t] = off[b * NBUCK + t]; cnt[t] = 0; }
    __syncthreads();
    int base = b * CHUNK;
#pragma unroll
    for (int j = 0; j < CHUNK / 256; ++j) {
        int e = base + j * 256 + t;
        if (e < E) {
            int s, d;
            if (is64) { s = raw[2 * e]; d = raw[2 * (E + e)]; }
            else      { s = raw[e];     d = raw[E + e]; }
            int k = d >> 8;
            int r = atomicAdd(&cnt[k], 1);
            ebuf[offl[k] + r] = ((unsigned int)(d & 255) << 16) | (unsigned int)s;
        }
    }
}

// ---------------- pass 4: per-bucket deg/rowp/dinv + fine scatter (u16 csr) --
__global__ __launch_bounds__(256) void bucket_fine2(const unsigned int* __restrict__ ebuf,
                                                    const int* __restrict__ bstart,
                                                    int* __restrict__ rowp,
                                                    float* __restrict__ dinv,
                                                    unsigned short* __restrict__ csr,
                                                    int n, int E) {
    __shared__ int cnt[256];
    __shared__ int pre[256];
    __shared__ int fil[256];
    int k = blockIdx.x, t = threadIdx.x;
    int base = k << 8;
    int nn = min(256, n - base);
    int es = bstart[k], ee = bstart[k + 1];
    cnt[t] = 0;
    __syncthreads();
    for (int p = es + t; p < ee; p += 256) atomicAdd(&cnt[ebuf[p] >> 16], 1);
    __syncthreads();
    pre[t] = cnt[t];
    __syncthreads();
    for (int o = 1; o < 256; o <<= 1) {
        int v = (t >= o) ? pre[t - o] : 0;
        __syncthreads();
        pre[t] += v;
        __syncthreads();
    }
    int excl = (t == 0) ? 0 : pre[t - 1];
    if (t < nn) {
        rowp[base + t] = es + excl;
        dinv[base + t] = rsqrtf((float)(cnt[t] + 1));  // +1 = self-loop
    }
    if (k == gridDim.x - 1 && t == 0) rowp[n] = E;
    fil[t] = es + excl;
    __syncthreads();
    for (int p = es + t; p < ee; p += 256) {
        unsigned int u = ebuf[p];
        int q = atomicAdd(&fil[u >> 16], 1);
        csr[q] = (unsigned short)(u & 0xFFFFu);
    }
}

// ---------------- weight pack: W[K][128] f32 -> fragment-order split bf16 -----
__global__ void pack_w(const float* __restrict__ W, int K,
                       unsigned short* __restrict__ ph, unsigned short* __restrict__ pl) {
    int gid = blockIdx.x * 256 + threadIdx.x;
    int total = (K / 32) * 8 * 64;
    if (gid >= total) return;
    int l = gid & 63;
    int c0 = (gid >> 6) & 7;
    int t = gid >> 9;
    int col = c0 * 16 + (l & 15);
    int k0 = t * 32 + ((l >> 4) << 3);
    size_t base = (size_t)gid * 8;
#pragma unroll
    for (int j = 0; j < 8; ++j) {
        unsigned short h, lo;
        split_bf16(W[(size_t)(k0 + j) * 128 + col], h, lo);
        ph[base + j] = h;
        pl[base + j] = lo;
    }
}

template <bool AHALF>
__device__ inline float4 loadA4(const void* A, size_t idx) {
    if constexpr (AHALF) {
        uint2 u = *(const uint2*)((const __half*)A + idx);
        float2 f0 = __half22float2(*(__half2*)&u.x);
        float2 f1 = __half22float2(*(__half2*)&u.y);
        return make_float4(f0.x, f0.y, f1.x, f1.y);
    } else {
        return *(const float4*)((const float*)A + idx);
    }
}

// ------- split-bf16 MFMA GEMM: ht[M,128] = dinv ⊙ (A[M,K] @ B[K,128]), fp16 --
template <int K, bool AHALF>
__global__ __launch_bounds__(256) void gemm_mfma2(const void* __restrict__ A,
                                                  const unsigned short* __restrict__ Bph,
                                                  const unsigned short* __restrict__ Bpl,
                                                  const float* __restrict__ dinv,
                                                  __half* __restrict__ Chalf, int M) {
    __shared__ unsigned short Ah[64][40];  // 32 + 8 pad
    __shared__ unsigned short Al[64][40];
    int tid = threadIdx.x;
    int wid = tid >> 6, lane = tid & 63;
    int wr = wid >> 1, wc = wid & 1;      // wave grid 2x2
    int row0 = blockIdx.x * 64;
    int lrow = lane & 15, lk = (lane >> 4) * 8;
    const int T = K / 32;

    int sidx0 = tid, sidx1 = 256 + tid;
    int sr0 = sidx0 >> 3, sc0 = (sidx0 & 7) * 4;
    int sr1 = sidx1 >> 3, sc1 = (sidx1 & 7) * 4;
    bool v0 = (row0 + sr0) < M, v1 = (row0 + sr1) < M;
    size_t ai0 = (size_t)(row0 + sr0) * K + sc0;
    size_t ai1 = (size_t)(row0 + sr1) * K + sc1;

    float4 pre0 = make_float4(0.f, 0.f, 0.f, 0.f), pre1 = pre0;
    if (v0) pre0 = loadA4<AHALF>(A, ai0);
    if (v1) pre1 = loadA4<AHALF>(A, ai1);

    f32x4 acc[2][4] = {};
    for (int t = 0; t < T; ++t) {
        u16x4 h, lo;
        split_bf16(pre0.x, ((unsigned short*)&h)[0], ((unsigned short*)&lo)[0]);
        split_bf16(pre0.y, ((unsigned short*)&h)[1], ((unsigned short*)&lo)[1]);
        split_bf16(pre0.z, ((unsigned short*)&h)[2], ((unsigned short*)&lo)[2]);
        split_bf16(pre0.w, ((unsigned short*)&h)[3], ((unsigned short*)&lo)[3]);
        *(u16x4*)&Ah[sr0][sc0] = h;
        *(u16x4*)&Al[sr0][sc0] = lo;
        split_bf16(pre1.x, ((unsigned short*)&h)[0], ((unsigned short*)&lo)[0]);
        split_bf16(pre1.y, ((unsigned short*)&h)[1], ((unsigned short*)&lo)[1]);
        split_bf16(pre1.z, ((unsigned short*)&h)[2], ((unsigned short*)&lo)[2]);
        split_bf16(pre1.w, ((unsigned short*)&h)[3], ((unsigned short*)&lo)[3]);
        *(u16x4*)&Ah[sr1][sc1] = h;
        *(u16x4*)&Al[sr1][sc1] = lo;
        __syncthreads();
        if (t + 1 < T) {
            pre0 = make_float4(0.f, 0.f, 0.f, 0.f); pre1 = pre0;
            if (v0) pre0 = loadA4<AHALF>(A, ai0 + (size_t)(t + 1) * 32);
            if (v1) pre1 = loadA4<AHALF>(A, ai1 + (size_t)(t + 1) * 32);
        }
        bf16x8 ah[2], al[2];
#pragma unroll
        for (int m = 0; m < 2; ++m) {
            int r = wr * 32 + m * 16 + lrow;
            ah[m] = *(const bf16x8*)&Ah[r][lk];
            al[m] = *(const bf16x8*)&Al[r][lk];
        }
        bf16x8 bh[4], bl[4];
#pragma unroll
        for (int n = 0; n < 4; ++n) {
            size_t boff = ((size_t)(t * 8 + wc * 4 + n) * 64 + lane) * 8;
            bh[n] = *(const bf16x8*)&Bph[boff];
            bl[n] = *(const bf16x8*)&Bpl[boff];
        }
#pragma unroll
        for (int m = 0; m < 2; ++m)
#pragma unroll
            for (int n = 0; n < 4; ++n) {
                acc[m][n] = __builtin_amdgcn_mfma_f32_16x16x32_bf16(ah[m], bh[n], acc[m][n], 0, 0, 0);
                acc[m][n] = __builtin_amdgcn_mfma_f32_16x16x32_bf16(al[m], bh[n], acc[m][n], 0, 0, 0);
                acc[m][n] = __builtin_amdgcn_mfma_f32_16x16x32_bf16(ah[m], bl[n], acc[m][n], 0, 0, 0);
            }
        __syncthreads();
    }
    // epilogue: ht = dinv[r] * acc, fp16. C/D layout: col=lane&15, row=(lane>>4)*4+j
#pragma unroll
    for (int m = 0; m < 2; ++m) {
        int rbase = row0 + wr * 32 + m * 16 + (lane >> 4) * 4;
#pragma unroll
        for (int n = 0; n < 4; ++n) {
            int col = wc * 64 + n * 16 + lrow;
#pragma unroll
            for (int j = 0; j < 4; ++j) {
                int r = rbase + j;
                if (r < M) Chalf[(size_t)r * 128 + col] = __float2half(dinv[r] * acc[m][n][j]);
            }
        }
    }
}

// ------- aggregation: wave-per-node, pre-scaled fp16 table, unroll-16 --------
// out[i] = relu(di * (ht[i] + sum_s ht[s]) + b), written fp16
__global__ __launch_bounds__(256) void aggregate5(const __half* __restrict__ ht,
                                                  const int* __restrict__ rowp,
                                                  const unsigned short* __restrict__ csr,
                                                  const float* __restrict__ dinv,
                                                  const float* __restrict__ bias,
                                                  __half* __restrict__ outh, int n) {
    int wid = threadIdx.x >> 6, lane = threadIdx.x & 63;
    int i = blockIdx.x * 4 + wid;
    if (i >= n) return;
    const __half2* h2 = (const __half2*)ht;  // [n][64] half2
    float di = dinv[i];
    float2 acc = __half22float2(h2[(size_t)i * 64 + lane]);  // self (pre-scaled)
    int b = rowp[i], e = rowp[i + 1];
    int p = b;
    for (; p + 16 <= e; p += 16) {
        int s[16]; float2 v[16];
#pragma unroll
        for (int q = 0; q < 16; ++q) s[q] = csr[p + q];
#pragma unroll
        for (int q = 0; q < 16; ++q) v[q] = __half22float2(h2[(size_t)s[q] * 64 + lane]);
#pragma unroll
        for (int q = 0; q < 16; ++q) { acc.x += v[q].x; acc.y += v[q].y; }
    }
    for (; p + 4 <= e; p += 4) {
        int s[4]; float2 v[4];
#pragma unroll
        for (int q = 0; q < 4; ++q) s[q] = csr[p + q];
#pragma unroll
        for (int q = 0; q < 4; ++q) v[q] = __half22float2(h2[(size_t)s[q] * 64 + lane]);
#pragma unroll
        for (int q = 0; q < 4; ++q) { acc.x += v[q].x; acc.y += v[q].y; }
    }
    for (; p < e; ++p) {
        float2 v = __half22float2(h2[(size_t)csr[p] * 64 + lane]);
        acc.x += v.x;
        acc.y += v.y;
    }
    float2 bb = ((const float2*)bias)[lane];
    __half2 o = __floats2half2_rn(fmaxf(di * acc.x + bb.x, 0.f),
                                  fmaxf(di * acc.y + bb.y, 0.f));
    ((__half2*)outh)[(size_t)i * 64 + lane] = o;
}

// ---------------- final FC: out[N,32] = h(fp16)[N,128] @ Wfc[128,32] + bfc ---
__global__ __launch_bounds__(256) void fc_out(const __half* __restrict__ h,
                                              const float* __restrict__ W,
                                              const float* __restrict__ b,
                                              float* __restrict__ out, int n) {
    __shared__ float Ws[HID * NCLS];
    __shared__ float Hs[8][HID];
    int tid = threadIdx.x;
#pragma unroll
    for (int l = 0; l < 16; ++l) Ws[l * 256 + tid] = W[l * 256 + tid];
    int row0 = blockIdx.x * 8;
#pragma unroll
    for (int l = 0; l < 4; ++l) {
        int idx = l * 256 + tid;
        int r = idx >> 7, c = idx & 127;
        int gr = row0 + r;
        Hs[r][c] = (gr < n) ? __half2float(h[(size_t)gr * HID + c]) : 0.f;
    }
    __syncthreads();
    int r = tid >> 5, c = tid & 31;
    float acc = b[c];
#pragma unroll
    for (int k = 0; k < HID; ++k) acc += Hs[r][k] * Ws[k * NCLS + c];
    int gr = row0 + r;
    if (gr < n) out[(size_t)gr * NCLS + c] = acc;
}

extern "C" void kernel_launch(void* const* d_in, const int* in_sizes, int n_in,
                              void* d_out, int out_size, void* d_ws, size_t ws_size,
                              hipStream_t stream) {
    const float* x   = (const float*)d_in[0];
    const int*   eid = (const int*)d_in[1];
    const float* W1  = (const float*)d_in[2];
    const float* b1  = (const float*)d_in[3];
    const float* W2  = (const float*)d_in[4];
    const float* b2  = (const float*)d_in[5];
    const float* Wfc = (const float*)d_in[6];
    const float* bfc = (const float*)d_in[7];
    float* out = (float*)d_out;

    const int N = N_NODES;
    const int E = in_sizes[1] / 2;
    const int NBLK = (E + CHUNK - 1) / CHUNK;

    auto align = [](size_t v) { return (v + 255) & ~(size_t)255; };
    char* w = (char*)d_ws;
    size_t off = 0;
    int* rowp = (int*)(w + off);           off = align(off + (size_t)(N + 1) * 4);
    float* dinv = (float*)(w + off);       off = align(off + (size_t)N * 4);
    unsigned short* csr = (unsigned short*)(w + off); off = align(off + (size_t)E * 2);
    unsigned int* ebuf = (unsigned int*)(w + off);    off = align(off + (size_t)E * 4);
    int* bstart = (int*)(w + off);         off = align(off + (size_t)(NBUCK + 1) * 4);
    int* hist = (int*)(w + off);           off = align(off + (size_t)NBLK * NBUCK * 4);
    int* offs = (int*)(w + off);           off = align(off + (size_t)NBLK * NBUCK * 4);
    unsigned short* W1ph = (unsigned short*)(w + off); off = align(off + (size_t)128 * IN_DIM * 2);
    unsigned short* W1pl = (unsigned short*)(w + off); off = align(off + (size_t)128 * IN_DIM * 2);
    unsigned short* W2ph = (unsigned short*)(w + off); off = align(off + (size_t)128 * HID * 2);
    unsigned short* W2pl = (unsigned short*)(w + off); off = align(off + (size_t)128 * HID * 2);
    __half* ht1 = (__half*)(w + off);      off = align(off + (size_t)N * HID * 2);
    __half* ht2 = (__half*)(w + off);      off = align(off + (size_t)N * HID * 2);
    __half* h1r = (__half*)(w + off);      off = align(off + (size_t)N * HID * 2);
    __half* h2r = (__half*)(w + off);      off = align(off + (size_t)N * HID * 2);

    count_bucket<<<NBLK, 256, 0, stream>>>(eid, E, hist);
    scan_off2<<<1, 256, 0, stream>>>(hist, NBLK, E, bstart, offs);
    chunk_scatter<<<NBLK, 256, 0, stream>>>(eid, E, offs, ebuf);
    bucket_fine2<<<NBUCK, 256, 0, stream>>>(ebuf, bstart, rowp, dinv, csr, N, E);

    pack_w<<<((IN_DIM / 32) * 8 * 64 + 255) / 256, 256, 0, stream>>>(W1, IN_DIM, W1ph, W1pl);
    pack_w<<<((HID / 32) * 8 * 64 + 255) / 256, 256, 0, stream>>>(W2, HID, W2ph, W2pl);

    int gb = (N + 63) / 64;
    int ab = (N + 3) / 4;
    gemm_mfma2<IN_DIM, false><<<gb, 256, 0, stream>>>(x, W1ph, W1pl, dinv, ht1, N);
    aggregate5<<<ab, 256, 0, stream>>>(ht1, rowp, csr, dinv, b1, h1r, N);
    gemm_mfma2<HID, true><<<gb, 256, 0, stream>>>(h1r, W2ph, W2pl, dinv, ht2, N);
    aggregate5<<<ab, 256, 0, stream>>>(ht2, rowp, csr, dinv, b2, h2r, N);
    fc_out<<<(N + 7) / 8, 256, 0, stream>>>(h2r, Wfc, bfc, out, N);
}